// Round 2
// baseline (619.303 us; speedup 1.0000x reference)
//
#include <hip/hip_runtime.h>

#define VR_EPS 1e-10f
#define VR_S 128   // samples per ray
#define SPL 8      // samples per lane
#define LPR 16     // lanes per ray (16 segments of 8 samples)

// 16 lanes per ray, 8 samples per lane, 4 rays per wave.
__global__ __launch_bounds__(256) void vr_kernel(
    const float* __restrict__ alpha,   // [R, 128]
    const float* __restrict__ rgbs,    // [R, 128, 3]
    float* __restrict__ out_rgb,       // [R, 3]
    float* __restrict__ out_w,         // [R, 128]
    int n_rays)
{
    const int tid  = blockIdx.x * blockDim.x + threadIdx.x;
    const int lane = threadIdx.x & 63;
    const int seg  = lane & (LPR - 1);     // segment index within the ray
    const int ray  = tid >> 4;             // 16 lanes per ray
    if (ray >= n_rays) return;

    // ---- alpha: two aligned float4 loads (32B per lane, fully coalesced) ----
    const size_t abase = (size_t)ray * VR_S + seg * SPL;
    const float4 a0 = *(const float4*)(alpha + abase);
    const float4 a1 = *(const float4*)(alpha + abase + 4);

    float a[SPL] = {a0.x, a0.y, a0.z, a0.w, a1.x, a1.y, a1.z, a1.w};
    float t[SPL];
    #pragma unroll
    for (int i = 0; i < SPL; ++i) t[i] = 1.0f - a[i] + VR_EPS;

    // per-lane product of its 8 transmittance terms
    float P = t[0];
    #pragma unroll
    for (int i = 1; i < SPL; ++i) P *= t[i];

    // ---- product scan across the 16 segments of this ray ----
    float inc = P;
    #pragma unroll
    for (int off = 1; off < LPR; off <<= 1) {
        float up = __shfl_up(inc, off, 64);
        inc *= (seg >= off) ? up : 1.0f;
    }
    float exc = __shfl_up(inc, 1, 64);   // exclusive prefix over segments
    if (seg == 0) exc = 1.0f;

    // per-sample transmittance within the segment
    float pre[SPL];
    pre[0] = exc;
    #pragma unroll
    for (int i = 1; i < SPL; ++i) pre[i] = pre[i - 1] * t[i - 1];

    float w[SPL];
    #pragma unroll
    for (int i = 0; i < SPL; ++i) w[i] = pre[i] * a[i];

    // ---- weights out: two aligned float4 stores ----
    *(float4*)(out_w + abase)     = make_float4(w[0], w[1], w[2], w[3]);
    *(float4*)(out_w + abase + 4) = make_float4(w[4], w[5], w[6], w[7]);

    // ---- rgbs: six aligned float4 loads (96B per lane, 16B-aligned) ----
    const float* rp = rgbs + (size_t)ray * (VR_S * 3) + seg * (SPL * 3);
    float cf[SPL * 3];
    #pragma unroll
    for (int i = 0; i < 6; ++i) {
        const float4 v = *(const float4*)(rp + 4 * i);
        cf[4 * i + 0] = v.x; cf[4 * i + 1] = v.y;
        cf[4 * i + 2] = v.z; cf[4 * i + 3] = v.w;
    }

    float r = 0.f, g = 0.f, b = 0.f;
    #pragma unroll
    for (int i = 0; i < SPL; ++i) {
        r += w[i] * cf[3 * i + 0];
        g += w[i] * cf[3 * i + 1];
        b += w[i] * cf[3 * i + 2];
    }

    // ---- butterfly reduce across the 16 lanes of this ray ----
    #pragma unroll
    for (int off = 8; off >= 1; off >>= 1) {
        r += __shfl_xor(r, off, 64);
        g += __shfl_xor(g, off, 64);
        b += __shfl_xor(b, off, 64);
    }
    if (seg == 0) {
        float* op = out_rgb + (size_t)ray * 3;
        op[0] = r; op[1] = g; op[2] = b;
    }
}

extern "C" void kernel_launch(void* const* d_in, const int* in_sizes, int n_in,
                              void* d_out, int out_size, void* d_ws, size_t ws_size,
                              hipStream_t stream) {
    const float* alpha = (const float*)d_in[0];
    const float* rgbs  = (const float*)d_in[1];
    const int n_rays = in_sizes[0] / VR_S;

    float* out_rgb = (float*)d_out;                       // first R*3 floats
    float* out_w   = (float*)d_out + (size_t)n_rays * 3;  // then R*128 floats

    const long long total_threads = (long long)n_rays * LPR;
    const int blocks = (int)((total_threads + 255) / 256);
    vr_kernel<<<blocks, 256, 0, stream>>>(alpha, rgbs, out_rgb, out_w, n_rays);
}